// Round 2
// baseline (25928.659 us; speedup 1.0000x reference)
//
#include <hip/hip_runtime.h>
#include <stdint.h>

#define B_ 64
#define S_ 1024
#define I_ 512
#define H_ 1024
#define O_ 256

typedef float f32x4 __attribute__((ext_vector_type(4)));
typedef short s16x8 __attribute__((ext_vector_type(8)));
typedef _Float16 h16x8 __attribute__((ext_vector_type(8)));

__device__ __forceinline__ float bf2f(unsigned short u) {
    union { unsigned int i; float f; } c; c.i = ((unsigned int)u) << 16; return c.f;
}
__device__ __forceinline__ unsigned short f2bf(float f) {
    union { float f; unsigned int i; } c; c.f = f;
    unsigned int u = c.i;
    return (unsigned short)((u + 0x7fffu + ((u >> 16) & 1u)) >> 16);
}

// ---- dtype-agnostic load/store helpers (isf32 is wave-uniform -> scalar branch) ----
__device__ __forceinline__ h16x8 load8_h(const void* p, size_t eidx, int isf32) {
    h16x8 r;
    if (isf32) {
        const float* f = (const float*)p + eidx;
        const f32x4 a = *(const f32x4*)f;
        const f32x4 b = *(const f32x4*)(f + 4);
        r[0] = (_Float16)a[0]; r[1] = (_Float16)a[1]; r[2] = (_Float16)a[2]; r[3] = (_Float16)a[3];
        r[4] = (_Float16)b[0]; r[5] = (_Float16)b[1]; r[6] = (_Float16)b[2]; r[7] = (_Float16)b[3];
    } else {
        const s16x8 v = *(const s16x8*)((const unsigned short*)p + eidx);
#pragma unroll
        for (int e = 0; e < 8; ++e) r[e] = (_Float16)bf2f((unsigned short)v[e]);
    }
    return r;
}
__device__ __forceinline__ float load1_f(const void* p, size_t eidx, int isf32) {
    return isf32 ? ((const float*)p)[eidx] : bf2f(((const unsigned short*)p)[eidx]);
}
__device__ __forceinline__ void store1_o(void* p, size_t eidx, float v, int isf32) {
    if (isf32) ((float*)p)[eidx] = v;
    else       ((unsigned short*)p)[eidx] = f2bf(v);
}

// ---- dtype probe: bf16 low-half has exponent-like bits14..7; fp32 has uniform mantissa there ----
__global__ void detect_kernel(const unsigned int* __restrict__ x, unsigned int* __restrict__ flag) {
    int lane = threadIdx.x;  // 64 lanes read 256 words
    int cnt = 0;
#pragma unroll
    for (int i = 0; i < 4; ++i) {
        unsigned int w = x[lane * 4 + i];
        unsigned int e2 = (w >> 7) & 0xFFu;
        cnt += (e2 >= 110u && e2 <= 135u) ? 1 : 0;
    }
#pragma unroll
    for (int d = 1; d < 64; d <<= 1) cnt += __shfl_xor(cnt, d);
    if (lane == 0) *flag = (cnt < 160) ? 1u : 0u;  // 1 = fp32, 0 = bf16
}

__global__ void zero_kernel(unsigned int* p, int n) {
    int i = blockIdx.x * blockDim.x + threadIdx.x;
    for (; i < n; i += gridDim.x * blockDim.x) p[i] = 0u;
}

// ---------------- Fused scan: h_{t+1} = tanh(x_t Wx^T + b + h_t Wh^T) ----------------
// 256 WGs x 64 threads. Group g (of 4) owns batches [16g,16g+16); WG j (of 64) owns cols [16j,16j+16).
// LDS: Wh slice fp16 32KB + Wx slice fp16 16KB + h stage 32KB = 80KB -> 2 WG/CU, all 256 co-resident.
__global__ __launch_bounds__(64) void scan_kernel(
        const void* __restrict__ x, const void* __restrict__ Wx,
        const void* __restrict__ Wh, const void* __restrict__ bias,
        _Float16* __restrict__ hbuf, void* __restrict__ out,
        unsigned int* __restrict__ counters, const unsigned int* __restrict__ flagp)
{
    __shared__ _Float16 whs[16 * 1024];
    __shared__ _Float16 wxs[16 * 512];
    __shared__ _Float16 hs[16 * 1024];
    const int tid = threadIdx.x;
    const int g = blockIdx.x >> 6;   // 0..3  batch group
    const int j = blockIdx.x & 63;   // 0..63 col tile
    const int l15 = tid & 15, quad = tid >> 4;
    const int isf32 = (int)*flagp;

    // Preload Wh rows [16j,16j+16) -> fp16, XOR-swizzled 16B blocks (2-way bank aliasing = free).
    for (int c = tid; c < 2048; c += 64) {
        int n = c >> 7, kb = c & 127;
        h16x8 v = load8_h(Wh, (size_t)(j * 16 + n) * H_ + kb * 8, isf32);
        *(h16x8*)&whs[n * 1024 + ((kb ^ (n & 7)) * 8)] = v;
    }
    // Preload Wx rows [16j,16j+16) (K=512 -> 64 blocks of 8).
    for (int c = tid; c < 1024; c += 64) {
        int n = c >> 6, kb = c & 63;
        h16x8 v = load8_h(Wx, (size_t)(j * 16 + n) * I_ + kb * 8, isf32);
        *(h16x8*)&wxs[n * 512 + ((kb ^ (n & 7)) * 8)] = v;
    }
    const float bv = load1_f(bias, j * 16 + l15, isf32);
    unsigned int* cnt = counters + g * 64;

    for (int t = 0; t < S_; ++t) {
        // stage this group's h_t tile [16 x 1024] into LDS (t=0 reads zeros)
        const _Float16* hsrc = hbuf + ((size_t)(t & 1)) * B_ * H_ + (size_t)g * 16 * H_;
#pragma unroll 8
        for (int c = tid; c < 2048; c += 64) {
            int m = c >> 7, kb = c & 127;
            h16x8 v = *(const h16x8*)(hsrc + (size_t)m * H_ + kb * 8);
            *(h16x8*)&hs[m * 1024 + ((kb ^ (m & 7)) * 8)] = v;
        }
        __syncthreads();

        f32x4 acc = (f32x4)0.0f;
        // x-projection: A = x[b, t, :] straight from global, B = Wx slice in LDS. K=512 -> 16 MFMAs.
#pragma unroll 4
        for (int ks = 0; ks < 16; ++ks) {
            h16x8 a = load8_h(x, ((size_t)(g * 16 + l15) * S_ + t) * I_ + ks * 32 + quad * 8, isf32);
            int kb = (ks * 4 + quad) ^ (l15 & 7);
            h16x8 w = *(const h16x8*)&wxs[l15 * 512 + kb * 8];
            acc = __builtin_amdgcn_mfma_f32_16x16x32_f16(a, w, acc, 0, 0, 0);
        }
        // recurrence: h_t . Wh^T. K=1024 -> 32 MFMAs.
#pragma unroll 8
        for (int ks = 0; ks < 32; ++ks) {
            int kb = (ks * 4 + quad) ^ (l15 & 7);
            h16x8 a = *(const h16x8*)&hs[l15 * 1024 + kb * 8];
            h16x8 w = *(const h16x8*)&whs[l15 * 1024 + kb * 8];
            acc = __builtin_amdgcn_mfma_f32_16x16x32_f16(a, w, acc, 0, 0, 0);
        }

        // h_new = tanh(acc + bias); publish fp16 (recurrence) + output dtype (all_outs)
        _Float16* hdst = hbuf + ((size_t)((t + 1) & 1)) * B_ * H_;
        const int col = j * 16 + l15;
#pragma unroll
        for (int r = 0; r < 4; ++r) {
            int brow = g * 16 + quad * 4 + r;
            float hv = tanhf(acc[r] + bv);
            hdst[(size_t)brow * H_ + col] = (_Float16)hv;
            store1_o(out, (size_t)B_ * O_ + ((size_t)t * B_ + brow) * H_ + col, hv, isf32);
        }

        // inter-WG group barrier with device-scope visibility (cross-XCD L2 non-coherence, G16)
        __threadfence();          // writeback: make this wave's h stores visible device-wide
        __syncthreads();
        if (tid == 0) {
            __hip_atomic_fetch_add(cnt, 1u, __ATOMIC_RELEASE, __HIP_MEMORY_SCOPE_AGENT);
            unsigned int target = 64u * (unsigned int)(t + 1);
            while (__hip_atomic_load(cnt, __ATOMIC_ACQUIRE, __HIP_MEMORY_SCOPE_AGENT) < target)
                __builtin_amdgcn_s_sleep(1);
        }
        __syncthreads();
        __threadfence();          // invalidate: next stage loads must see other WGs' h
    }
}

// ---------------- Readout: y = h_last @ Wout^T + bout ----------------
__global__ __launch_bounds__(64) void readout_kernel(
        const _Float16* __restrict__ hfin, const void* __restrict__ Wout,
        const void* __restrict__ bout, void* __restrict__ y,
        const unsigned int* __restrict__ flagp)
{
    const int tid = threadIdx.x;
    const int tm = blockIdx.x & 3, tn = blockIdx.x >> 2;
    const int l15 = tid & 15, quad = tid >> 4;
    const int isf32 = (int)*flagp;
    f32x4 acc = (f32x4)0.0f;
#pragma unroll 4
    for (int ks = 0; ks < 32; ++ks) {
        h16x8 a = *(const h16x8*)(hfin + (size_t)(tm * 16 + l15) * H_ + ks * 32 + quad * 8);
        h16x8 w = load8_h(Wout, (size_t)(tn * 16 + l15) * H_ + ks * 32 + quad * 8, isf32);
        acc = __builtin_amdgcn_mfma_f32_16x16x32_f16(a, w, acc, 0, 0, 0);
    }
    const int col = tn * 16 + l15;
    const float bo = load1_f(bout, col, isf32);
#pragma unroll
    for (int r = 0; r < 4; ++r) {
        int row = tm * 16 + quad * 4 + r;
        store1_o(y, (size_t)row * O_ + col, acc[r] + bo, isf32);
    }
}

extern "C" void kernel_launch(void* const* d_in, const int* in_sizes, int n_in,
                              void* d_out, int out_size, void* d_ws, size_t ws_size,
                              hipStream_t stream)
{
    const void* x    = d_in[0];
    const void* Wx   = d_in[1];
    const void* Wh   = d_in[2];
    const void* bias = d_in[3];
    const void* Wout = d_in[4];
    const void* bout = d_in[5];

    // ws layout (tiny, ~266 KB): h double-buffer fp16 | barrier counters | dtype flag
    const size_t HBUF_BYTES = (size_t)2 * B_ * H_ * 2;   // 262144
    const size_t CNT_BYTES  = 4096;
    char* w = (char*)d_ws;
    _Float16*     hbuf     = (_Float16*)w;
    unsigned int* counters = (unsigned int*)(w + HBUF_BYTES);
    unsigned int* flag     = (unsigned int*)(w + HBUF_BYTES + CNT_BYTES);

    zero_kernel<<<128, 256, 0, stream>>>((unsigned int*)w, (int)((HBUF_BYTES + CNT_BYTES) / 4));
    detect_kernel<<<1, 64, 0, stream>>>((const unsigned int*)x, flag);

    scan_kernel<<<256, 64, 0, stream>>>(x, Wx, Wh, bias, hbuf, d_out, counters, flag);
    // after S_=1024 (even) steps, final h is in buffer 0
    readout_kernel<<<64, 64, 0, stream>>>(hbuf, Wout, bout, d_out, flag);
}